// Round 20
// baseline (3056.333 us; speedup 1.0000x reference)
//
#include <hip/hip_runtime.h>
#include <hip/hip_bf16.h>
#include <cstdint>
#include <cstddef>

typedef unsigned short u16;
typedef unsigned int u32;
typedef __attribute__((ext_vector_type(8))) short short8;
typedef __attribute__((ext_vector_type(4))) short short4v;
typedef __attribute__((ext_vector_type(4))) float f32x4;

__device__ __forceinline__ u16 f2bf(float f) {
  u32 u = __float_as_uint(f);
  u32 r = (u + 0x7FFFu + ((u >> 16) & 1u)) >> 16;   // RNE
  return (u16)r;
}
__device__ __forceinline__ float bf2f(u16 u) {
  return __uint_as_float(((u32)u) << 16);
}
// compiler-native RNE f32->bf16 (enables v_cvt_pk_bf16_f32 pairing)
__device__ __forceinline__ short f2bf_hw(float f) {
  union { __hip_bfloat16 h; u16 u; } c;
  c.h = __float2bfloat16(f);
  return (short)c.u;
}

__device__ __forceinline__ void gload_lds16(const void* g, void* l) {
  __builtin_amdgcn_global_load_lds((const __attribute__((address_space(1))) void*)g,
                                   (__attribute__((address_space(3))) void*)l, 16, 0, 0);
}

// ---------------------------------------------------------------- GEMM ------
// C[M,N] = A_bf16[M,K] @ W[N,K]^T  (+ rank-8 LoRA + bias + residual)
// Best-measured config (3036us): single-buffered 32KB LDS, WMODE=1 bf16
// weights DMA'd like A (0 bank conflicts), 2-barrier K-loop with prefetch
// under MFMA. WMODE=0: fp32 weights (projector only).
// SIDECAR: leading grid-y blocks stream-convert fp32->bf16 weights for
// LATER launches using idle HBM bandwidth (dispatched FIRST).
struct ConvJob { const float* src; u16* dst; long n8; };
struct GemmArgs {
  const u16* A; int M; int K; int lda;
  const float* W0; const float* LB0; int toff0;
  const float* W1; const float* LB1; int toff1;
  const float* W2; const float* LB2; int toff2;
  const u16* Wb0; const u16* Wb1; const u16* Wb2;   // bf16 weights (WMODE=1)
  int ldw;
  int seg1; int seg2;            // global-n where W1/W2 begin (0 = unused)
  const float* t;                // lora t, stride 32 floats, or null
  const float* bias;             // or null
  const float* resid;            // stride 4096, or null
  float* outf; int ostride;      // fp32 out (if non-null)
  u16* outb0; u16* outb1;        // bf16 outs: n<seg1 -> outb0, else outb1
  int rowremap;                  // projector h-row remap
  float* outp;                   // split-K partial out (raw acc), z-strided
  int ny_main;                   // main grid-y count (sidecar blocks = rest)
  ConvJob cj[3];                 // sidecar conversion jobs
};

template<int WMODE>
__global__ __launch_bounds__(256) void gemm_kernel(GemmArgs a) {
  __shared__ u16 Asm[128 * 64];                      // 16KB bf16, DMA dest
  __shared__ u16 BsmW[WMODE ? 128 * 64 : 128 * 128]; // 16KB bf16 | 32KB fp32
  const int tid = threadIdx.x;

  // ---- conversion sidecar (FIRST in dispatch order) ----
  const int nconv = (int)gridDim.y - a.ny_main;
  if ((int)blockIdx.y < nconv) {
    if (blockIdx.z != 0) return;
    const long cb = (long)blockIdx.y * gridDim.x + blockIdx.x;
    const long cstr = (long)nconv * gridDim.x * 256;
#pragma unroll
    for (int j = 0; j < 3; j++) {
      const float* src = a.cj[j].src;
      if (!src) break;
      u16* dst = a.cj[j].dst;
      const long n8 = a.cj[j].n8;
      for (long i = cb * 256 + tid; i < n8; i += cstr) {
        const float* p = src + i * 8;
        float4 v0 = *(const float4*)p;
        float4 v1 = *(const float4*)(p + 4);
        uint4 w;
        w.x = (u32)(u16)f2bf_hw(v0.x) | ((u32)(u16)f2bf_hw(v0.y) << 16);
        w.y = (u32)(u16)f2bf_hw(v0.z) | ((u32)(u16)f2bf_hw(v0.w) << 16);
        w.z = (u32)(u16)f2bf_hw(v1.x) | ((u32)(u16)f2bf_hw(v1.y) << 16);
        w.w = (u32)(u16)f2bf_hw(v1.z) | ((u32)(u16)f2bf_hw(v1.w) << 16);
        *(uint4*)(dst + i * 8) = w;
      }
    }
    return;
  }
  const int yid = (int)blockIdx.y - nconv;           // main-grid y

  // XCD-chunked bijective swizzle (m204) over the MAIN grid only
  const int nwg = gridDim.x * a.ny_main;
  const int bid0 = yid * gridDim.x + blockIdx.x;
  const int q = nwg >> 3, r = nwg & 7;
  const int xcd = bid0 & 7, pos = bid0 >> 3;
  const int nb = (xcd < r ? xcd * (q + 1) : r * (q + 1) + (xcd - r) * q) + pos;
  const int m0 = (nb % gridDim.x) * 128;
  const int n0 = (nb / gridDim.x) * 128;

  const float* W = a.W0; const u16* Wb = a.Wb0;
  const float* LB = a.LB0; int toff = a.toff0; int nbase = 0;
  if (a.seg2 && n0 >= a.seg2)      { W = a.W2; Wb = a.Wb2; LB = a.LB2; toff = a.toff2; nbase = a.seg2; }
  else if (a.seg1 && n0 >= a.seg1) { W = a.W1; Wb = a.Wb1; LB = a.LB1; toff = a.toff1; nbase = a.seg1; }
  const int koff = blockIdx.z * a.K;                 // split-K slice
  const u16* Ab = a.A + koff;
  const float* Wt = W + (size_t)(n0 - nbase) * a.ldw + koff;
  const u16* Wbt = Wb + (size_t)(n0 - nbase) * a.ldw + koff;

  const int lane = tid & 63, wid = tid >> 6;
  const int wr = wid >> 1, wcn = wid & 1;
  const int lrow = lane & 15, g = lane >> 4;
  const int arow = lane >> 3;                        // DMA: row in 8-row chunk
  const int aslot = (lane & 7) ^ arow;               // swizzled source slot
  const int brow4 = lane >> 4;                       // fp32 B DMA row-in-4

  f32x4 acc[4][4] = {};

  auto dma_A = [&](int k0) {
#pragma unroll
    for (int i = 0; i < 4; i++) {
      int c = wid * 4 + i;                           // 8-row chunk id
      const u16* src = Ab + (size_t)(m0 + c * 8 + arow) * a.lda + k0 + (aslot << 3);
      gload_lds16(src, &Asm[c * 512]);
    }
  };
  auto dma_B = [&](int k0) {
    if (WMODE) {                                     // bf16: mirror of dma_A
#pragma unroll
      for (int i = 0; i < 4; i++) {
        int c = wid * 4 + i;
        const u16* src = Wbt + (size_t)(c * 8 + arow) * a.ldw + k0 + (aslot << 3);
        gload_lds16(src, &BsmW[c * 512]);
      }
    } else {                                         // fp32: 4-row groups
      float* Bf = (float*)BsmW;
#pragma unroll
      for (int j = 0; j < 8; j++) {
        int rrow = wid * 32 + j * 4 + brow4;
        int sslot = (lane & 15) ^ (rrow & 7);
        const float* src = Wt + (size_t)rrow * a.ldw + k0 + (sslot << 2);
        gload_lds16(src, &Bf[(wid * 32 + j * 4) * 64]);
      }
    }
  };

  dma_A(0);
  dma_B(0);
  const int nk = a.K >> 6;
  for (int kt = 0; kt < nk; kt++) {
    __syncthreads();                 // drains vmcnt(0): both DMAs landed

    short8 af[4][2], bq[4][2];
#pragma unroll
    for (int mi = 0; mi < 4; mi++) {
      int row = wr * 64 + mi * 16 + lrow;
#pragma unroll
      for (int x = 0; x < 2; x++) {
        int s = x * 4 + g;
        af[mi][x] = *(const short8*)&Asm[row * 64 + ((s ^ (lrow & 7)) << 3)];
      }
    }
#pragma unroll
    for (int ni = 0; ni < 4; ni++) {
      int row = wcn * 64 + ni * 16 + lrow;
      if (WMODE) {
#pragma unroll
        for (int x = 0; x < 2; x++) {
          int s = x * 4 + g;
          bq[ni][x] = *(const short8*)&BsmW[row * 64 + ((s ^ (lrow & 7)) << 3)];
        }
      } else {
        const float* bp = (const float*)BsmW + row * 64;
        int m = row & 7;
#pragma unroll
        for (int x = 0; x < 2; x++) {
          int sg0 = x * 8 + g * 2;                   // 16B-slot of k0=x*32+g*8
          f32x4 lo = *(const f32x4*)(bp + ((sg0 ^ m) << 2));
          f32x4 hi = *(const f32x4*)(bp + (((sg0 + 1) ^ m) << 2));
          short8 sv;
          sv[0] = f2bf_hw(lo[0]); sv[1] = f2bf_hw(lo[1]);
          sv[2] = f2bf_hw(lo[2]); sv[3] = f2bf_hw(lo[3]);
          sv[4] = f2bf_hw(hi[0]); sv[5] = f2bf_hw(hi[1]);
          sv[6] = f2bf_hw(hi[2]); sv[7] = f2bf_hw(hi[3]);
          bq[ni][x] = sv;
        }
      }
    }

    asm volatile("s_waitcnt lgkmcnt(0)" ::: "memory");   // own LDS reads done
    __builtin_amdgcn_sched_barrier(0);
    __builtin_amdgcn_s_barrier();    // all waves done reading
    __builtin_amdgcn_sched_barrier(0);
    if (kt + 1 < nk) {               // prefetch next tile under MFMA
      dma_A((kt + 1) << 6);
      dma_B((kt + 1) << 6);
    }
#pragma unroll
    for (int x = 0; x < 2; x++)
#pragma unroll
      for (int mi = 0; mi < 4; mi++)
#pragma unroll
        for (int ni = 0; ni < 4; ni++)
          acc[mi][ni] = __builtin_amdgcn_mfma_f32_16x16x32_bf16(af[mi][x], bq[ni][x], acc[mi][ni], 0, 0, 0);
  }

  // ---- epilogue ----
  if (a.outp) {                      // split-K partial: raw acc only
    float* op = a.outp + (size_t)blockIdx.z * (1536 * 4096);
#pragma unroll
    for (int mi = 0; mi < 4; mi++)
#pragma unroll
      for (int rr = 0; rr < 4; rr++) {
        int row = m0 + wr * 64 + mi * 16 + (g << 2) + rr;
#pragma unroll
        for (int ni = 0; ni < 4; ni++) {
          int n = n0 + wcn * 64 + ni * 16 + lrow;
          op[(size_t)row * a.ostride + n] = acc[mi][ni][rr];
        }
      }
    return;
  }
  const bool dolora = (a.t != nullptr);
  float lbv[4][8];
#pragma unroll
  for (int ni = 0; ni < 4; ni++) {
    if (dolora) {
      int cl = wcn * 64 + ni * 16 + lrow;
      const float* bp = LB + (size_t)(n0 - nbase + cl) * 8;
#pragma unroll
      for (int r2 = 0; r2 < 8; r2++) lbv[ni][r2] = bp[r2];
    }
  }
#pragma unroll
  for (int mi = 0; mi < 4; mi++) {
#pragma unroll
    for (int rr = 0; rr < 4; rr++) {
      int row = m0 + wr * 64 + mi * 16 + (g << 2) + rr;
      if (row >= a.M) continue;
      float tv[8];
      if (dolora) {
        const float* tp = a.t + row * 32 + toff;
#pragma unroll
        for (int r2 = 0; r2 < 8; r2++) tv[r2] = tp[r2];
      }
#pragma unroll
      for (int ni = 0; ni < 4; ni++) {
        int n = n0 + wcn * 64 + ni * 16 + lrow;
        float val = acc[mi][ni][rr];
        if (dolora) {
          float ds = 0.f;
#pragma unroll
          for (int r2 = 0; r2 < 8; r2++) ds += tv[r2] * lbv[ni][r2];
          val += 4.0f * ds;
        }
        if (a.bias)  val += a.bias[n];
        if (a.resid) val += a.resid[(size_t)row * 4096 + n];
        if (a.outf) {
          int orow = a.rowremap ? (row < 257 ? row : row + 511) : row;
          a.outf[(size_t)orow * a.ostride + n] = val;
        } else if (a.seg1 && n >= a.seg1) {
          a.outb1[(size_t)row * a.ostride + (n - a.seg1)] = f2bf(val);
        } else {
          a.outb0[(size_t)row * a.ostride + n] = f2bf(val);
        }
      }
    }
  }
}

// ---------------------------------------------- split-K combine (+lora) -----
__global__ __launch_bounds__(256) void combine_kernel(float* __restrict__ h,
    const float* __restrict__ p, const float* __restrict__ t,
    const float* __restrict__ LB) {
  const int row = blockIdx.x;
  float tv[8];
  const float* tp = t + row * 32;
#pragma unroll
  for (int r = 0; r < 8; r++) tv[r] = tp[r];
  const float* p1 = p + (size_t)1536 * 4096;
#pragma unroll
  for (int i = 0; i < 4; i++) {
    int base = threadIdx.x * 4 + i * 1024;
    size_t off = (size_t)row * 4096 + base;
    float4 hv = *(const float4*)(h + off);
    float4 a0 = *(const float4*)(p + off);
    float4 a1 = *(const float4*)(p1 + off);
    float o[4] = {hv.x + a0.x + a1.x, hv.y + a0.y + a1.y,
                  hv.z + a0.z + a1.z, hv.w + a0.w + a1.w};
#pragma unroll
    for (int j = 0; j < 4; j++) {
      const float* lb = LB + (size_t)(base + j) * 8;
      float ds = 0.f;
#pragma unroll
      for (int r = 0; r < 8; r++) ds += tv[r] * lb[r];
      o[j] += 4.0f * ds;
    }
    float4 ov; ov.x = o[0]; ov.y = o[1]; ov.z = o[2]; ov.w = o[3];
    *(float4*)(h + off) = ov;
  }
}

// --------------------------------------------------------------- LoRA xA^T --
template<int NA>
__global__ __launch_bounds__(256) void lora_xa_kernel(const u16* __restrict__ X, int K,
    const float* A0, const float* A1, const float* A2, float* __restrict__ t) {
  const int m = blockIdx.x;
  const u16* xr = X + (size_t)m * K;
  float acc[NA * 8];
#pragma unroll
  for (int i = 0; i < NA * 8; i++) acc[i] = 0.f;
  const float* Ap[3] = {A0, A1, A2};
  for (int k = threadIdx.x * 8; k < K; k += 2048) {
    uint4 xv = *(const uint4*)(xr + k);
    float xf[8];
    xf[0] = bf2f((u16)(xv.x & 0xffff)); xf[1] = bf2f((u16)(xv.x >> 16));
    xf[2] = bf2f((u16)(xv.y & 0xffff)); xf[3] = bf2f((u16)(xv.y >> 16));
    xf[4] = bf2f((u16)(xv.z & 0xffff)); xf[5] = bf2f((u16)(xv.z >> 16));
    xf[6] = bf2f((u16)(xv.w & 0xffff)); xf[7] = bf2f((u16)(xv.w >> 16));
#pragma unroll
    for (int aa = 0; aa < NA; aa++) {
#pragma unroll
      for (int r = 0; r < 8; r++) {
        const float* ar = Ap[aa] + (size_t)r * K + k;
        float4 a0 = *(const float4*)ar;
        float4 a1 = *(const float4*)(ar + 4);
        acc[aa * 8 + r] += xf[0] * a0.x + xf[1] * a0.y + xf[2] * a0.z + xf[3] * a0.w
                         + xf[4] * a1.x + xf[5] * a1.y + xf[6] * a1.z + xf[7] * a1.w;
      }
    }
  }
  __shared__ float red[4][NA * 8];
#pragma unroll
  for (int i = 0; i < NA * 8; i++) {
    float v = acc[i];
#pragma unroll
    for (int o = 1; o < 64; o <<= 1) v += __shfl_xor(v, o);
    if ((threadIdx.x & 63) == 0) red[threadIdx.x >> 6][i] = v;
  }
  __syncthreads();
  if (threadIdx.x < NA * 8)
    t[m * 32 + threadIdx.x] = red[0][threadIdx.x] + red[1][threadIdx.x]
                            + red[2][threadIdx.x] + red[3][threadIdx.x];
}

// --------------------------------- fused SiLU(g)*u -> x2 + down-LoRA t ------
// Same k-stride accumulation pattern as lora_xa (identical summation order);
// lora dot uses the bf16-rounded x2 values exactly as the unfused pair did.
__global__ __launch_bounds__(256) void gu_lora_kernel(const u16* __restrict__ g,
    const u16* __restrict__ u, u16* __restrict__ x2,
    const float* __restrict__ Ad, float* __restrict__ t) {
  const int m = blockIdx.x, tid = threadIdx.x;
  float acc[8];
#pragma unroll
  for (int r = 0; r < 8; r++) acc[r] = 0.f;
  const size_t rb = (size_t)m * 14336;
  for (int k = tid * 8; k < 14336; k += 2048) {
    uint4 gv = *(const uint4*)(g + rb + k);
    uint4 uv = *(const uint4*)(u + rb + k);
    u32 gi[4] = {gv.x, gv.y, gv.z, gv.w};
    u32 ui[4] = {uv.x, uv.y, uv.z, uv.w};
    u32 oi[4];
    float xf[8];
#pragma unroll
    for (int i = 0; i < 4; i++) {
      float g0 = bf2f((u16)(gi[i] & 0xffff)), g1 = bf2f((u16)(gi[i] >> 16));
      float u0 = bf2f((u16)(ui[i] & 0xffff)), u1 = bf2f((u16)(ui[i] >> 16));
      float s0 = g0 / (1.f + __expf(-g0)) * u0;
      float s1 = g1 / (1.f + __expf(-g1)) * u1;
      u16 b0 = f2bf(s0), b1 = f2bf(s1);
      oi[i] = (u32)b0 | ((u32)b1 << 16);
      xf[2 * i] = bf2f(b0); xf[2 * i + 1] = bf2f(b1);
    }
    uint4 ov; ov.x = oi[0]; ov.y = oi[1]; ov.z = oi[2]; ov.w = oi[3];
    *(uint4*)(x2 + rb + k) = ov;
#pragma unroll
    for (int r = 0; r < 8; r++) {
      const float* ar = Ad + (size_t)r * 14336 + k;
      float4 a0 = *(const float4*)ar;
      float4 a1 = *(const float4*)(ar + 4);
      acc[r] += xf[0] * a0.x + xf[1] * a0.y + xf[2] * a0.z + xf[3] * a0.w
              + xf[4] * a1.x + xf[5] * a1.y + xf[6] * a1.z + xf[7] * a1.w;
    }
  }
  __shared__ float red[4][8];
#pragma unroll
  for (int i = 0; i < 8; i++) {
    float v = acc[i];
#pragma unroll
    for (int o = 1; o < 64; o <<= 1) v += __shfl_xor(v, o);
    if ((tid & 63) == 0) red[tid >> 6][i] = v;
  }
  __syncthreads();
  if (tid < 8)
    t[m * 32 + tid] = red[0][tid] + red[1][tid] + red[2][tid] + red[3][tid];
}

// ---------------------------------------------------------------- RMSNorm ---
__global__ __launch_bounds__(256) void rmsnorm_kernel(const float* __restrict__ h,
    const float* __restrict__ w, u16* outb, float* outf) {
  const int m = blockIdx.x;
  const float* row = h + (size_t)m * 4096;
  float4 v[4];
  float ss = 0.f;
#pragma unroll
  for (int i = 0; i < 4; i++) {
    v[i] = *(const float4*)(row + threadIdx.x * 4 + i * 1024);
    ss += v[i].x * v[i].x + v[i].y * v[i].y + v[i].z * v[i].z + v[i].w * v[i].w;
  }
#pragma unroll
  for (int o = 1; o < 64; o <<= 1) ss += __shfl_xor(ss, o);
  __shared__ float red[4];
  if ((threadIdx.x & 63) == 0) red[threadIdx.x >> 6] = ss;
  __syncthreads();
  ss = red[0] + red[1] + red[2] + red[3];
  float rs = rsqrtf(ss * (1.f / 4096.f) + 1e-5f);
#pragma unroll
  for (int i = 0; i < 4; i++) {
    int base = threadIdx.x * 4 + i * 1024;
    float4 wv = *(const float4*)(w + base);
    float o0 = v[i].x * rs * wv.x, o1 = v[i].y * rs * wv.y;
    float o2 = v[i].z * rs * wv.z, o3 = v[i].w * rs * wv.w;
    if (outb) {
      short4v sv; sv.x = (short)f2bf(o0); sv.y = (short)f2bf(o1);
      sv.z = (short)f2bf(o2); sv.w = (short)f2bf(o3);
      *(short4v*)(outb + (size_t)m * 4096 + base) = sv;
    } else {
      float4 ov; ov.x = o0; ov.y = o1; ov.z = o2; ov.w = o3;
      *(float4*)(outf + (size_t)m * 4096 + base) = ov;
    }
  }
}

// ------------------------------------------------------------------- RoPE ---
__global__ void rope_tab_kernel(float2* __restrict__ tab) {
  int idx = blockIdx.x * 256 + threadIdx.x;   // 768*64
  int s = idx >> 6, i = idx & 63;
  float inv = __expf(-(float)i * (9.210340371976184f / 64.f));  // 10000^(-i/64)
  float ang = (float)s * inv;
  float sn, cs;
  sincosf(ang, &sn, &cs);
  float2 r; r.x = cs; r.y = sn;
  tab[idx] = r;
}

// ---------------------------- MFMA flash attention with fused RoPE ----------
// Q roped at fragment load (pairs col, col+64); K roped during staging
// (partner at c4^64). Same fp32 rope formulas as the old rope_apply, then
// the same f2bf — numerics unchanged. V untouched.
__global__ __launch_bounds__(256) void attn_mfma_kernel(const float* __restrict__ qkv,
    const int* __restrict__ amask, const float2* __restrict__ tab,
    u16* __restrict__ attn_bf) {
  __shared__ u16 Ks[4][32][40];   // [kslice][key][8k-frag slots + pad]
  __shared__ u16 Vt[128][40];     // [d][key]
  __shared__ u16 Ps[4][16][40];   // per-wave [qrow][key]
  const int b = blockIdx.z, hh = blockIdx.y, q0 = blockIdx.x * 64;
  const int kvh = hh >> 2;
  const int tid = threadIdx.x, lane = tid & 63, w = tid >> 6;
  const int lrow = lane & 15, g = lane >> 4;
  const float sc = 0.08838834764831845f;   // 1/sqrt(128)

  const int spos = q0 + w * 16 + lrow;     // position within batch (0..767)
  short8 qf[4];
  {
    const float* qp = qkv + ((size_t)(b * 768 + spos)) * 6144 + hh * 128;
#pragma unroll
    for (int ks = 0; ks < 2; ks++) {
      int c0 = ks * 32 + g * 8;            // < 64
      float4 lo  = *(const float4*)(qp + c0);
      float4 hi  = *(const float4*)(qp + c0 + 4);
      float4 plo = *(const float4*)(qp + c0 + 64);
      float4 phi = *(const float4*)(qp + c0 + 68);
      float x[8] = {lo.x, lo.y, lo.z, lo.w, hi.x, hi.y, hi.z, hi.w};
      float p[8] = {plo.x, plo.y, plo.z, plo.w, phi.x, phi.y, phi.z, phi.w};
      short8 aa, bb;
#pragma unroll
      for (int j = 0; j < 8; j++) {
        float2 cs = tab[spos * 64 + c0 + j];
        aa[j] = f2bf_hw((x[j] * cs.x - p[j] * cs.y) * sc);
        bb[j] = f2bf_hw((p[j] * cs.x + x[j] * cs.y) * sc);
      }
      qf[ks] = aa; qf[ks + 2] = bb;
    }
  }

  f32x4 acco[8] = {};
  float mrun[4] = {-1e30f, -1e30f, -1e30f, -1e30f};
  float lrun[4] = {0.f, 0.f, 0.f, 0.f};
  const int ntile = (q0 >> 5) + 2;

  for (int kt = 0; kt < ntile; kt++) {
    const int k0 = kt * 32;
    __syncthreads();
#pragma unroll
    for (int i = 0; i < 4; i++) {
      int idx = i * 256 + tid;
      int r2 = idx >> 5, c4 = (idx & 31) << 2;
      const float* kbase = qkv + ((size_t)(b * 768 + k0 + r2)) * 6144 + 4096 + kvh * 128;
      float4 kv = *(const float4*)(kbase + c4);
      float4 pv = *(const float4*)(kbase + (c4 ^ 64));
      int ci = c4 & 63;
      float2 t0 = tab[(k0 + r2) * 64 + ci];
      float2 t1 = tab[(k0 + r2) * 64 + ci + 1];
      float2 t2 = tab[(k0 + r2) * 64 + ci + 2];
      float2 t3 = tab[(k0 + r2) * 64 + ci + 3];
      float sgn = (c4 < 64) ? -1.f : 1.f;
      short4v ksv;
      ksv.x = f2bf_hw(kv.x * t0.x + sgn * (pv.x * t0.y));
      ksv.y = f2bf_hw(kv.y * t1.x + sgn * (pv.y * t1.y));
      ksv.z = f2bf_hw(kv.z * t2.x + sgn * (pv.z * t2.y));
      ksv.w = f2bf_hw(kv.w * t3.x + sgn * (pv.w * t3.y));
      *(short4v*)&Ks[c4 >> 5][r2][c4 & 31] = ksv;
      float4 vv = *(const float4*)(kbase + 1024 + c4);
      Vt[c4 + 0][r2] = (u16)f2bf_hw(vv.x);
      Vt[c4 + 1][r2] = (u16)f2bf_hw(vv.y);
      Vt[c4 + 2][r2] = (u16)f2bf_hw(vv.z);
      Vt[c4 + 3][r2] = (u16)f2bf_hw(vv.w);
    }
    __syncthreads();

    f32x4 s0 = {}, s1 = {};
#pragma unroll
    for (int ks = 0; ks < 4; ks++) {
      short8 kb0 = *(const short8*)&Ks[ks][lrow][g * 8];
      short8 kb1 = *(const short8*)&Ks[ks][16 + lrow][g * 8];
      s0 = __builtin_amdgcn_mfma_f32_16x16x32_bf16(qf[ks], kb0, s0, 0, 0, 0);
      s1 = __builtin_amdgcn_mfma_f32_16x16x32_bf16(qf[ks], kb1, s1, 0, 0, 0);
    }
    const int key0 = k0 + lrow, key1 = k0 + 16 + lrow;
    const bool am0 = amask[b * 768 + key0] != 0;
    const bool am1 = amask[b * 768 + key1] != 0;
    float scl4[4];
#pragma unroll
    for (int rr = 0; rr < 4; rr++) {
      int qrow = q0 + w * 16 + g * 4 + rr;
      float v0 = (key0 <= qrow && am0) ? s0[rr] : -1e30f;
      float v1 = (key1 <= qrow && am1) ? s1[rr] : -1e30f;
      float m = fmaxf(v0, v1);
      m = fmaxf(m, __shfl_xor(m, 1));
      m = fmaxf(m, __shfl_xor(m, 2));
      m = fmaxf(m, __shfl_xor(m, 4));
      m = fmaxf(m, __shfl_xor(m, 8));
      float mnew = fmaxf(mrun[rr], m);
      float scl = __expf(mrun[rr] - mnew);
      float p0 = __expf(v0 - mnew);
      float p1 = __expf(v1 - mnew);
      float ls = p0 + p1;
      ls += __shfl_xor(ls, 1);
      ls += __shfl_xor(ls, 2);
      ls += __shfl_xor(ls, 4);
      ls += __shfl_xor(ls, 8);
      lrun[rr] = lrun[rr] * scl + ls;
      mrun[rr] = mnew;
      scl4[rr] = scl;
      Ps[w][g * 4 + rr][lrow]      = (u16)f2bf_hw(p0);
      Ps[w][g * 4 + rr][16 + lrow] = (u16)f2bf_hw(p1);
    }
#pragma unroll
    for (int nf = 0; nf < 8; nf++)
#pragma unroll
      for (int rr = 0; rr < 4; rr++) acco[nf][rr] *= scl4[rr];

    asm volatile("s_waitcnt lgkmcnt(0)" ::: "memory");   // Ps writes landed
    __builtin_amdgcn_sched_barrier(0);
    short8 pa = *(const short8*)&Ps[w][lrow][g * 8];
#pragma unroll
    for (int nf = 0; nf < 8; nf++) {
      short8 vb = *(const short8*)&Vt[nf * 16 + lrow][g * 8];
      acco[nf] = __builtin_amdgcn_mfma_f32_16x16x32_bf16(pa, vb, acco[nf], 0, 0, 0);
    }
  }

#pragma unroll
  for (int rr = 0; rr < 4; rr++) {
    float inv = 1.f / lrun[rr];
    size_t orow = (size_t)(b * 768 + q0 + w * 16 + g * 4 + rr);
#pragma unroll
    for (int nf = 0; nf < 8; nf++)
      attn_bf[orow * 4096 + hh * 128 + nf * 16 + lrow] = f2bf(acco[nf][rr] * inv);
  }
}

// ------------------------------------------------------------ small utils ---
__global__ void convert_img_kernel(const float* __restrict__ in, u16* __restrict__ out) {
  int idx = blockIdx.x * 256 + threadIdx.x;   // chunks of 8; 640*1024/8 = 81920
  if (idx >= 81920) return;
  uint4 w = {0u, 0u, 0u, 0u};
  if (idx < 65792) {                          // real data: 514*1024/8
    const float* p = in + (size_t)idx * 8;
    float4 v0 = *(const float4*)p;
    float4 v1 = *(const float4*)(p + 4);
    w.x = (u32)f2bf(v0.x) | ((u32)f2bf(v0.y) << 16);
    w.y = (u32)f2bf(v0.z) | ((u32)f2bf(v0.w) << 16);
    w.z = (u32)f2bf(v1.x) | ((u32)f2bf(v1.y) << 16);
    w.w = (u32)f2bf(v1.z) | ((u32)f2bf(v1.w) << 16);
  }
  *(uint4*)(out + (size_t)idx * 8) = w;       // zero-fill pad rows 514..639
}

__global__ void embed_gather_kernel(const float* __restrict__ embed,
    const int* __restrict__ ids, float* __restrict__ h) {
  int row = blockIdx.x;                 // 0..1021
  int b = row / 511, tt = row % 511;
  int id = ids[b * 511 + tt];
  const float* src = embed + (size_t)id * 4096;
  float* dst = h + ((size_t)(b * 768 + 257 + tt)) * 4096;
  for (int i = threadIdx.x * 4; i < 4096; i += 1024)
    *(float4*)(dst + i) = *(const float4*)(src + i);
}

// ------------------------------------------------------------------ host ----
extern "C" void kernel_launch(void* const* d_in, const int* in_sizes, int n_in,
                              void* d_out, int out_size, void* d_ws, size_t ws_size,
                              hipStream_t stream) {
  const float* image_embeds = (const float*)d_in[0];
  const int*   input_ids    = (const int*)d_in[1];
  const int*   amask        = (const int*)d_in[2];
  const float* proj_W = (const float*)d_in[3];
  const float* proj_b = (const float*)d_in[4];
  const float* embed  = (const float*)d_in[5];
  const float* ln1 = (const float*)d_in[6];
  const float* ln2 = (const float*)d_in[7];
  const float* ln_f = (const float*)d_in[8];
  const float* Wq = (const float*)d_in[9];
  const float* Aq = (const float*)d_in[10];
  const float* Bq = (const float*)d_in[11];
  const float* Wk = (const float*)d_in[12];
  const float* Ak = (const float*)d_in[13];
  const float* Bk = (const float*)d_in[14];
  const float* Wv = (const float*)d_in[15];
  const float* Av = (const float*)d_in[16];
  const float* Bv = (const float*)d_in[17];
  const float* Wo = (const float*)d_in[18];
  const float* Ao = (const float*)d_in[19];
  const float* Bo = (const float*)d_in[20];
  const float* Wg = (const float*)d_in[21];
  const float* Ag = (const float*)d_in[22];
  const float* Bg = (const float*)d_in[23];
  const float* Wu = (const float*)d_in[24];
  const float* Au = (const float*)d_in[25];
  const float* Bu = (const float*)d_in[26];
  const float* Wd = (const float*)d_in[27];
  const float* Ad = (const float*)d_in[28];
  const float* Bd = (const float*)d_in[29];
  (void)in_sizes; (void)n_in; (void)out_size;

  char* ws = (char*)d_ws;
  size_t off = 0;
  auto alloc = [&](size_t bytes) -> void* {
    void* p = ws + off; off += (bytes + 255) & ~(size_t)255; return p;
  };
  float* h       = (float*) alloc((size_t)1536 * 4096 * 4);
  u16*   xn      = (u16*)   alloc((size_t)1536 * 4096 * 2);
  float* qkv     = (float*) alloc((size_t)1536 * 6144 * 4);
  u16*   attn_bf = (u16*)   alloc((size_t)1536 * 4096 * 2);
  u16*   g_bf    = (u16*)   alloc((size_t)1536 * 14336 * 2);
  u16*   u_bf    = (u16*)   alloc((size_t)1536 * 14336 * 2);
  u16*   x2_bf   = (u16*)   alloc((size_t)1536 * 14336 * 2);
  float* t       = (float*) alloc((size_t)1536 * 32 * 4);
  float2* tab    = (float2*)alloc((size_t)768 * 64 * 8);
  u16*   img_bf  = (u16*)   alloc((size_t)640 * 1024 * 2);       // 128-padded
  float* pc      = (float*) alloc((size_t)2 * 1536 * 4096 * 4);  // split-K partials
  // bf16 weight copies (all layers)
  const size_t nQ = (size_t)2 * 4096 * 4096;     // Wq / Wo
  const size_t nK = (size_t)2 * 1024 * 4096;     // Wk / Wv
  const size_t nG = (size_t)2 * 14336 * 4096;    // Wg / Wu / Wd
  const long nQl8 = 4096L * 4096 / 8, nKl8 = 1024L * 4096 / 8, nGl8 = 14336L * 4096 / 8;
  u16* wq_b = (u16*)alloc(nQ * 2);
  u16* wk_b = (u16*)alloc(nK * 2);
  u16* wv_b = (u16*)alloc(nK * 2);
  u16* wo_b = (u16*)alloc(nQ * 2);
  u16* wg_b = (u16*)alloc(nG * 2);
  u16* wu_b = (u16*)alloc(nG * 2);
  u16* wd_b = (u16*)alloc(nG * 2);
  const bool use_bf = (off <= ws_size);
  const int CONVY = 16;                          // sidecar y-blocks per launch

  dim3 blk(256);
  auto launch_gemm = [&](const GemmArgs& a, dim3 grid) {
    if (a.Wb0) gemm_kernel<1><<<grid, blk, 0, stream>>>(a);
    else       gemm_kernel<0><<<grid, blk, 0, stream>>>(a);
  };

  convert_img_kernel<<<dim3(320), blk, 0, stream>>>(image_embeds, img_bf);
  rope_tab_kernel<<<dim3(192), blk, 0, stream>>>(tab);

  { // projector -> h; sidecar: convert layer-0 Wq/Wk/Wv (consumed next launch)
    GemmArgs a = {};
    a.A = img_bf; a.M = 514; a.K = 1024; a.lda = 1024; a.ldw = 1024;
    a.W0 = proj_W;
    a.bias = proj_b;
    a.outf = h; a.ostride = 4096; a.rowremap = 1;
    a.ny_main = 32;
    dim3 grid(5, 32);
    if (use_bf) {
      a.cj[0] = {Wq, wq_b, nQl8};
      a.cj[1] = {Wk, wk_b, nKl8};
      a.cj[2] = {Wv, wv_b, nKl8};
      grid = dim3(5, 32 + 2 * CONVY);      // 160 sidecar blocks
    }
    launch_gemm(a, grid);
  }
  embed_gather_kernel<<<dim3(1022), blk, 0, stream>>>(embed, input_ids, h);

  for (int l = 0; l < 2; l++) {
    const float* Wq_l = Wq + (size_t)l * 4096 * 4096;
    const float* Aq_l = Aq + (size_t)l * 8 * 4096;
    const float* Bq_l = Bq + (size_t)l * 4096 * 8;
    const float* Wk_l = Wk + (size_t)l * 1024 * 4096;
    const float* Ak_l = Ak + (size_t)l * 8 * 4096;
    const float* Bk_l = Bk + (size_t)l * 1024 * 8;
    const float* Wv_l = Wv + (size_t)l * 1024 * 4096;
    const float* Av_l = Av + (size_t)l * 8 * 4096;
    const float* Bv_l = Bv + (size_t)l * 1024 * 8;
    const float* Wo_l = Wo + (size_t)l * 4096 * 4096;
    const float* Ao_l = Ao + (size_t)l * 8 * 4096;
    const float* Bo_l = Bo + (size_t)l * 4096 * 8;
    const float* Wg_l = Wg + (size_t)l * 14336 * 4096;
    const float* Ag_l = Ag + (size_t)l * 8 * 4096;
    const float* Bg_l = Bg + (size_t)l * 14336 * 8;
    const float* Wu_l = Wu + (size_t)l * 14336 * 4096;
    const float* Au_l = Au + (size_t)l * 8 * 4096;
    const float* Bu_l = Bu + (size_t)l * 14336 * 8;
    const float* Wd_l = Wd + (size_t)l * 4096 * 14336;
    const float* Ad_l = Ad + (size_t)l * 8 * 14336;
    const float* Bd_l = Bd + (size_t)l * 4096 * 8;
    u16* wq_bl = wq_b + (size_t)l * 4096 * 4096;
    u16* wk_bl = wk_b + (size_t)l * 1024 * 4096;
    u16* wv_bl = wv_b + (size_t)l * 1024 * 4096;
    u16* wo_bl = wo_b + (size_t)l * 4096 * 4096;
    u16* wg_bl = wg_b + (size_t)l * 14336 * 4096;
    u16* wu_bl = wu_b + (size_t)l * 14336 * 4096;
    u16* wd_bl = wd_b + (size_t)l * 14336 * 4096;

    rmsnorm_kernel<<<dim3(1536), blk, 0, stream>>>(h, ln1 + l * 4096, xn, (float*)nullptr);
    lora_xa_kernel<3><<<dim3(1536), blk, 0, stream>>>(xn, 4096, Aq_l, Ak_l, Av_l, t);
    { // fused QKV; sidecar: convert Wo_l, Wg_l
      GemmArgs a = {};
      a.A = xn; a.M = 1536; a.K = 4096; a.lda = 4096; a.ldw = 4096;
      a.W0 = Wq_l; a.LB0 = Bq_l; a.toff0 = 0;
      a.W1 = Wk_l; a.LB1 = Bk_l; a.toff1 = 8;
      a.W2 = Wv_l; a.LB2 = Bv_l; a.toff2 = 16;
      a.seg1 = 4096; a.seg2 = 5120;
      a.t = t; a.outf = qkv; a.ostride = 6144;
      a.ny_main = 48;
      dim3 grid(12, 48);
      if (use_bf) {
        a.Wb0 = wq_bl; a.Wb1 = wk_bl; a.Wb2 = wv_bl;
        a.cj[0] = {Wo_l, wo_bl, nQl8};
        a.cj[1] = {Wg_l, wg_bl, nGl8};
        grid = dim3(12, 48 + CONVY);
      }
      launch_gemm(a, grid);
    }
    attn_mfma_kernel<<<dim3(12, 32, 2), blk, 0, stream>>>(qkv, amask, tab, attn_bf);
    lora_xa_kernel<1><<<dim3(1536), blk, 0, stream>>>(attn_bf, 4096, Ao_l,
        (const float*)nullptr, (const float*)nullptr, t);
    { // O projection (split-K x2); sidecar: convert Wu_l
      GemmArgs a = {};
      a.A = attn_bf; a.M = 1536; a.K = 2048; a.lda = 4096; a.ldw = 4096;
      a.W0 = Wo_l;
      a.ostride = 4096; a.outp = pc;
      a.ny_main = 32;
      dim3 grid(12, 32, 2);
      if (use_bf) {
        a.Wb0 = wo_bl;
        a.cj[0] = {Wu_l, wu_bl, nGl8};
        grid = dim3(12, 32 + CONVY, 2);
      }
      launch_gemm(a, grid);
      combine_kernel<<<dim3(1536), blk, 0, stream>>>(h, pc, t, Bo_l);
    }
    rmsnorm_kernel<<<dim3(1536), blk, 0, stream>>>(h, ln2 + l * 4096, xn, (float*)nullptr);
    lora_xa_kernel<2><<<dim3(1536), blk, 0, stream>>>(xn, 4096, Ag_l, Au_l,
        (const float*)nullptr, t);
    { // fused gate+up; sidecar: convert Wd_l
      GemmArgs a = {};
      a.A = xn; a.M = 1536; a.K = 4096; a.lda = 4096; a.ldw = 4096;
      a.W0 = Wg_l; a.LB0 = Bg_l; a.toff0 = 0;
      a.W1 = Wu_l; a.LB1 = Bu_l; a.toff1 = 8;
      a.seg1 = 14336;
      a.t = t; a.outb0 = g_bf; a.outb1 = u_bf; a.ostride = 14336;
      a.ny_main = 224;
      dim3 grid(12, 224);
      if (use_bf) {
        a.Wb0 = wg_bl; a.Wb1 = wu_bl;
        a.cj[0] = {Wd_l, wd_bl, nGl8};
        grid = dim3(12, 224 + CONVY);
      }
      launch_gemm(a, grid);
    }
    // fused SiLU(g)*u -> x2 + down-LoRA t (replaces gu_combine + lora_xa<1>)
    gu_lora_kernel<<<dim3(1536), blk, 0, stream>>>(g_bf, u_bf, x2_bf, Ad_l, t);
    { // down projection (split-K x2); sidecar (l==0): convert layer-1 QKV w
      GemmArgs a = {};
      a.A = x2_bf; a.M = 1536; a.K = 7168; a.lda = 14336; a.ldw = 14336;
      a.W0 = Wd_l;
      a.ostride = 4096; a.outp = pc;
      a.ny_main = 32;
      dim3 grid(12, 32, 2);
      if (use_bf) {
        a.Wb0 = wd_bl;
        if (l == 0) {
          a.cj[0] = {Wq + (size_t)4096 * 4096, wq_b + (size_t)4096 * 4096, nQl8};
          a.cj[1] = {Wk + (size_t)1024 * 4096, wk_b + (size_t)1024 * 4096, nKl8};
          a.cj[2] = {Wv + (size_t)1024 * 4096, wv_b + (size_t)1024 * 4096, nKl8};
          grid = dim3(12, 32 + CONVY, 2);
        }
      }
      launch_gemm(a, grid);
      combine_kernel<<<dim3(1536), blk, 0, stream>>>(h, pc, t, Bd_l);
    }
  }
  rmsnorm_kernel<<<dim3(1536), blk, 0, stream>>>(h, ln_f, (u16*)nullptr, (float*)d_out);
}

// Round 21
// 3032.921 us; speedup vs baseline: 1.0077x; 1.0077x over previous
//
#include <hip/hip_runtime.h>
#include <hip/hip_bf16.h>
#include <cstdint>
#include <cstddef>

typedef unsigned short u16;
typedef unsigned int u32;
typedef __attribute__((ext_vector_type(8))) short short8;
typedef __attribute__((ext_vector_type(4))) short short4v;
typedef __attribute__((ext_vector_type(4))) float f32x4;

__device__ __forceinline__ u16 f2bf(float f) {
  u32 u = __float_as_uint(f);
  u32 r = (u + 0x7FFFu + ((u >> 16) & 1u)) >> 16;   // RNE
  return (u16)r;
}
__device__ __forceinline__ float bf2f(u16 u) {
  return __uint_as_float(((u32)u) << 16);
}
// compiler-native RNE f32->bf16 (enables v_cvt_pk_bf16_f32 pairing)
__device__ __forceinline__ short f2bf_hw(float f) {
  union { __hip_bfloat16 h; u16 u; } c;
  c.h = __float2bfloat16(f);
  return (short)c.u;
}

__device__ __forceinline__ void gload_lds16(const void* g, void* l) {
  __builtin_amdgcn_global_load_lds((const __attribute__((address_space(1))) void*)g,
                                   (__attribute__((address_space(3))) void*)l, 16, 0, 0);
}

// ---------------------------------------------------------------- GEMM ------
// C[M,N] = A_bf16[M,K] @ W[N,K]^T  (+ rank-8 LoRA + bias + residual)
// Best-measured config (3036us): single-buffered 32KB LDS, WMODE=1 bf16
// weights DMA'd like A (0 bank conflicts), 2-barrier K-loop with prefetch
// under MFMA. WMODE=0: fp32 weights (projector only).
// SIDECAR: leading grid-y blocks stream-convert fp32->bf16 weights for
// LATER launches using idle HBM bandwidth (dispatched FIRST).
struct ConvJob { const float* src; u16* dst; long n8; };
struct GemmArgs {
  const u16* A; int M; int K; int lda;
  const float* W0; const float* LB0; int toff0;
  const float* W1; const float* LB1; int toff1;
  const float* W2; const float* LB2; int toff2;
  const u16* Wb0; const u16* Wb1; const u16* Wb2;   // bf16 weights (WMODE=1)
  int ldw;
  int seg1; int seg2;            // global-n where W1/W2 begin (0 = unused)
  const float* t;                // lora t, stride 32 floats, or null
  const float* bias;             // or null
  const float* resid;            // stride 4096, or null
  float* outf; int ostride;      // fp32 out (if non-null)
  u16* outb0; u16* outb1;        // bf16 outs: n<seg1 -> outb0, else outb1
  int rowremap;                  // projector h-row remap
  float* outp;                   // split-K partial out (raw acc), z-strided
  int ny_main;                   // main grid-y count (sidecar blocks = rest)
  ConvJob cj[3];                 // sidecar conversion jobs
};

template<int WMODE>
__global__ __launch_bounds__(256) void gemm_kernel(GemmArgs a) {
  __shared__ u16 Asm[128 * 64];                      // 16KB bf16, DMA dest
  __shared__ u16 BsmW[WMODE ? 128 * 64 : 128 * 128]; // 16KB bf16 | 32KB fp32
  const int tid = threadIdx.x;

  // ---- conversion sidecar (FIRST in dispatch order) ----
  const int nconv = (int)gridDim.y - a.ny_main;
  if ((int)blockIdx.y < nconv) {
    if (blockIdx.z != 0) return;
    const long cb = (long)blockIdx.y * gridDim.x + blockIdx.x;
    const long cstr = (long)nconv * gridDim.x * 256;
#pragma unroll
    for (int j = 0; j < 3; j++) {
      const float* src = a.cj[j].src;
      if (!src) break;
      u16* dst = a.cj[j].dst;
      const long n8 = a.cj[j].n8;
      for (long i = cb * 256 + tid; i < n8; i += cstr) {
        const float* p = src + i * 8;
        float4 v0 = *(const float4*)p;
        float4 v1 = *(const float4*)(p + 4);
        uint4 w;
        w.x = (u32)(u16)f2bf_hw(v0.x) | ((u32)(u16)f2bf_hw(v0.y) << 16);
        w.y = (u32)(u16)f2bf_hw(v0.z) | ((u32)(u16)f2bf_hw(v0.w) << 16);
        w.z = (u32)(u16)f2bf_hw(v1.x) | ((u32)(u16)f2bf_hw(v1.y) << 16);
        w.w = (u32)(u16)f2bf_hw(v1.z) | ((u32)(u16)f2bf_hw(v1.w) << 16);
        *(uint4*)(dst + i * 8) = w;
      }
    }
    return;
  }
  const int yid = (int)blockIdx.y - nconv;           // main-grid y

  // XCD-chunked bijective swizzle (m204) over the MAIN grid only
  const int nwg = gridDim.x * a.ny_main;
  const int bid0 = yid * gridDim.x + blockIdx.x;
  const int q = nwg >> 3, r = nwg & 7;
  const int xcd = bid0 & 7, pos = bid0 >> 3;
  const int nb = (xcd < r ? xcd * (q + 1) : r * (q + 1) + (xcd - r) * q) + pos;
  const int m0 = (nb % gridDim.x) * 128;
  const int n0 = (nb / gridDim.x) * 128;

  const float* W = a.W0; const u16* Wb = a.Wb0;
  const float* LB = a.LB0; int toff = a.toff0; int nbase = 0;
  if (a.seg2 && n0 >= a.seg2)      { W = a.W2; Wb = a.Wb2; LB = a.LB2; toff = a.toff2; nbase = a.seg2; }
  else if (a.seg1 && n0 >= a.seg1) { W = a.W1; Wb = a.Wb1; LB = a.LB1; toff = a.toff1; nbase = a.seg1; }
  const int koff = blockIdx.z * a.K;                 // split-K slice
  const u16* Ab = a.A + koff;
  const float* Wt = W + (size_t)(n0 - nbase) * a.ldw + koff;
  const u16* Wbt = Wb + (size_t)(n0 - nbase) * a.ldw + koff;

  const int lane = tid & 63, wid = tid >> 6;
  const int wr = wid >> 1, wcn = wid & 1;
  const int lrow = lane & 15, g = lane >> 4;
  const int arow = lane >> 3;                        // DMA: row in 8-row chunk
  const int aslot = (lane & 7) ^ arow;               // swizzled source slot
  const int brow4 = lane >> 4;                       // fp32 B DMA row-in-4

  f32x4 acc[4][4] = {};

  auto dma_A = [&](int k0) {
#pragma unroll
    for (int i = 0; i < 4; i++) {
      int c = wid * 4 + i;                           // 8-row chunk id
      const u16* src = Ab + (size_t)(m0 + c * 8 + arow) * a.lda + k0 + (aslot << 3);
      gload_lds16(src, &Asm[c * 512]);
    }
  };
  auto dma_B = [&](int k0) {
    if (WMODE) {                                     // bf16: mirror of dma_A
#pragma unroll
      for (int i = 0; i < 4; i++) {
        int c = wid * 4 + i;
        const u16* src = Wbt + (size_t)(c * 8 + arow) * a.ldw + k0 + (aslot << 3);
        gload_lds16(src, &BsmW[c * 512]);
      }
    } else {                                         // fp32: 4-row groups
      float* Bf = (float*)BsmW;
#pragma unroll
      for (int j = 0; j < 8; j++) {
        int rrow = wid * 32 + j * 4 + brow4;
        int sslot = (lane & 15) ^ (rrow & 7);
        const float* src = Wt + (size_t)rrow * a.ldw + k0 + (sslot << 2);
        gload_lds16(src, &Bf[(wid * 32 + j * 4) * 64]);
      }
    }
  };

  dma_A(0);
  dma_B(0);
  const int nk = a.K >> 6;
  for (int kt = 0; kt < nk; kt++) {
    __syncthreads();                 // drains vmcnt(0): both DMAs landed

    short8 af[4][2], bq[4][2];
#pragma unroll
    for (int mi = 0; mi < 4; mi++) {
      int row = wr * 64 + mi * 16 + lrow;
#pragma unroll
      for (int x = 0; x < 2; x++) {
        int s = x * 4 + g;
        af[mi][x] = *(const short8*)&Asm[row * 64 + ((s ^ (lrow & 7)) << 3)];
      }
    }
#pragma unroll
    for (int ni = 0; ni < 4; ni++) {
      int row = wcn * 64 + ni * 16 + lrow;
      if (WMODE) {
#pragma unroll
        for (int x = 0; x < 2; x++) {
          int s = x * 4 + g;
          bq[ni][x] = *(const short8*)&BsmW[row * 64 + ((s ^ (lrow & 7)) << 3)];
        }
      } else {
        const float* bp = (const float*)BsmW + row * 64;
        int m = row & 7;
#pragma unroll
        for (int x = 0; x < 2; x++) {
          int sg0 = x * 8 + g * 2;                   // 16B-slot of k0=x*32+g*8
          f32x4 lo = *(const f32x4*)(bp + ((sg0 ^ m) << 2));
          f32x4 hi = *(const f32x4*)(bp + (((sg0 + 1) ^ m) << 2));
          short8 sv;
          sv[0] = f2bf_hw(lo[0]); sv[1] = f2bf_hw(lo[1]);
          sv[2] = f2bf_hw(lo[2]); sv[3] = f2bf_hw(lo[3]);
          sv[4] = f2bf_hw(hi[0]); sv[5] = f2bf_hw(hi[1]);
          sv[6] = f2bf_hw(hi[2]); sv[7] = f2bf_hw(hi[3]);
          bq[ni][x] = sv;
        }
      }
    }

    asm volatile("s_waitcnt lgkmcnt(0)" ::: "memory");   // own LDS reads done
    __builtin_amdgcn_sched_barrier(0);
    __builtin_amdgcn_s_barrier();    // all waves done reading
    __builtin_amdgcn_sched_barrier(0);
    if (kt + 1 < nk) {               // prefetch next tile under MFMA
      dma_A((kt + 1) << 6);
      dma_B((kt + 1) << 6);
    }
#pragma unroll
    for (int x = 0; x < 2; x++)
#pragma unroll
      for (int mi = 0; mi < 4; mi++)
#pragma unroll
        for (int ni = 0; ni < 4; ni++)
          acc[mi][ni] = __builtin_amdgcn_mfma_f32_16x16x32_bf16(af[mi][x], bq[ni][x], acc[mi][ni], 0, 0, 0);
  }

  // ---- epilogue ----
  if (a.outp) {                      // split-K partial: raw acc only
    float* op = a.outp + (size_t)blockIdx.z * (1536 * 4096);
#pragma unroll
    for (int mi = 0; mi < 4; mi++)
#pragma unroll
      for (int rr = 0; rr < 4; rr++) {
        int row = m0 + wr * 64 + mi * 16 + (g << 2) + rr;
#pragma unroll
        for (int ni = 0; ni < 4; ni++) {
          int n = n0 + wcn * 64 + ni * 16 + lrow;
          op[(size_t)row * a.ostride + n] = acc[mi][ni][rr];
        }
      }
    return;
  }
  const bool dolora = (a.t != nullptr);
  float lbv[4][8];
#pragma unroll
  for (int ni = 0; ni < 4; ni++) {
    if (dolora) {
      int cl = wcn * 64 + ni * 16 + lrow;
      const float* bp = LB + (size_t)(n0 - nbase + cl) * 8;
#pragma unroll
      for (int r2 = 0; r2 < 8; r2++) lbv[ni][r2] = bp[r2];
    }
  }
#pragma unroll
  for (int mi = 0; mi < 4; mi++) {
#pragma unroll
    for (int rr = 0; rr < 4; rr++) {
      int row = m0 + wr * 64 + mi * 16 + (g << 2) + rr;
      if (row >= a.M) continue;
      float tv[8];
      if (dolora) {
        const float* tp = a.t + row * 32 + toff;
#pragma unroll
        for (int r2 = 0; r2 < 8; r2++) tv[r2] = tp[r2];
      }
#pragma unroll
      for (int ni = 0; ni < 4; ni++) {
        int n = n0 + wcn * 64 + ni * 16 + lrow;
        float val = acc[mi][ni][rr];
        if (dolora) {
          float ds = 0.f;
#pragma unroll
          for (int r2 = 0; r2 < 8; r2++) ds += tv[r2] * lbv[ni][r2];
          val += 4.0f * ds;
        }
        if (a.bias)  val += a.bias[n];
        if (a.resid) val += a.resid[(size_t)row * 4096 + n];
        if (a.outf) {
          int orow = a.rowremap ? (row < 257 ? row : row + 511) : row;
          a.outf[(size_t)orow * a.ostride + n] = val;
        } else if (a.seg1 && n >= a.seg1) {
          a.outb1[(size_t)row * a.ostride + (n - a.seg1)] = f2bf(val);
        } else {
          a.outb0[(size_t)row * a.ostride + n] = f2bf(val);
        }
      }
    }
  }
}

// ---------------------------------------------- split-K combine (+lora) -----
__global__ __launch_bounds__(256) void combine_kernel(float* __restrict__ h,
    const float* __restrict__ p, const float* __restrict__ t,
    const float* __restrict__ LB) {
  const int row = blockIdx.x;
  float tv[8];
  const float* tp = t + row * 32;
#pragma unroll
  for (int r = 0; r < 8; r++) tv[r] = tp[r];
  const float* p1 = p + (size_t)1536 * 4096;
#pragma unroll
  for (int i = 0; i < 4; i++) {
    int base = threadIdx.x * 4 + i * 1024;
    size_t off = (size_t)row * 4096 + base;
    float4 hv = *(const float4*)(h + off);
    float4 a0 = *(const float4*)(p + off);
    float4 a1 = *(const float4*)(p1 + off);
    float o[4] = {hv.x + a0.x + a1.x, hv.y + a0.y + a1.y,
                  hv.z + a0.z + a1.z, hv.w + a0.w + a1.w};
#pragma unroll
    for (int j = 0; j < 4; j++) {
      const float* lb = LB + (size_t)(base + j) * 8;
      float ds = 0.f;
#pragma unroll
      for (int r = 0; r < 8; r++) ds += tv[r] * lb[r];
      o[j] += 4.0f * ds;
    }
    float4 ov; ov.x = o[0]; ov.y = o[1]; ov.z = o[2]; ov.w = o[3];
    *(float4*)(h + off) = ov;
  }
}

// --------------------------------------------------------------- LoRA xA^T --
template<int NA>
__global__ __launch_bounds__(256) void lora_xa_kernel(const u16* __restrict__ X, int K,
    const float* A0, const float* A1, const float* A2, float* __restrict__ t) {
  const int m = blockIdx.x;
  const u16* xr = X + (size_t)m * K;
  float acc[NA * 8];
#pragma unroll
  for (int i = 0; i < NA * 8; i++) acc[i] = 0.f;
  const float* Ap[3] = {A0, A1, A2};
  for (int k = threadIdx.x * 8; k < K; k += 2048) {
    uint4 xv = *(const uint4*)(xr + k);
    float xf[8];
    xf[0] = bf2f((u16)(xv.x & 0xffff)); xf[1] = bf2f((u16)(xv.x >> 16));
    xf[2] = bf2f((u16)(xv.y & 0xffff)); xf[3] = bf2f((u16)(xv.y >> 16));
    xf[4] = bf2f((u16)(xv.z & 0xffff)); xf[5] = bf2f((u16)(xv.z >> 16));
    xf[6] = bf2f((u16)(xv.w & 0xffff)); xf[7] = bf2f((u16)(xv.w >> 16));
#pragma unroll
    for (int aa = 0; aa < NA; aa++) {
#pragma unroll
      for (int r = 0; r < 8; r++) {
        const float* ar = Ap[aa] + (size_t)r * K + k;
        float4 a0 = *(const float4*)ar;
        float4 a1 = *(const float4*)(ar + 4);
        acc[aa * 8 + r] += xf[0] * a0.x + xf[1] * a0.y + xf[2] * a0.z + xf[3] * a0.w
                         + xf[4] * a1.x + xf[5] * a1.y + xf[6] * a1.z + xf[7] * a1.w;
      }
    }
  }
  __shared__ float red[4][NA * 8];
#pragma unroll
  for (int i = 0; i < NA * 8; i++) {
    float v = acc[i];
#pragma unroll
    for (int o = 1; o < 64; o <<= 1) v += __shfl_xor(v, o);
    if ((threadIdx.x & 63) == 0) red[threadIdx.x >> 6][i] = v;
  }
  __syncthreads();
  if (threadIdx.x < NA * 8)
    t[m * 32 + threadIdx.x] = red[0][threadIdx.x] + red[1][threadIdx.x]
                            + red[2][threadIdx.x] + red[3][threadIdx.x];
}

// ---------------------------------------------------------------- RMSNorm ---
__global__ __launch_bounds__(256) void rmsnorm_kernel(const float* __restrict__ h,
    const float* __restrict__ w, u16* outb, float* outf) {
  const int m = blockIdx.x;
  const float* row = h + (size_t)m * 4096;
  float4 v[4];
  float ss = 0.f;
#pragma unroll
  for (int i = 0; i < 4; i++) {
    v[i] = *(const float4*)(row + threadIdx.x * 4 + i * 1024);
    ss += v[i].x * v[i].x + v[i].y * v[i].y + v[i].z * v[i].z + v[i].w * v[i].w;
  }
#pragma unroll
  for (int o = 1; o < 64; o <<= 1) ss += __shfl_xor(ss, o);
  __shared__ float red[4];
  if ((threadIdx.x & 63) == 0) red[threadIdx.x >> 6] = ss;
  __syncthreads();
  ss = red[0] + red[1] + red[2] + red[3];
  float rs = rsqrtf(ss * (1.f / 4096.f) + 1e-5f);
#pragma unroll
  for (int i = 0; i < 4; i++) {
    int base = threadIdx.x * 4 + i * 1024;
    float4 wv = *(const float4*)(w + base);
    float o0 = v[i].x * rs * wv.x, o1 = v[i].y * rs * wv.y;
    float o2 = v[i].z * rs * wv.z, o3 = v[i].w * rs * wv.w;
    if (outb) {
      short4v sv; sv.x = (short)f2bf(o0); sv.y = (short)f2bf(o1);
      sv.z = (short)f2bf(o2); sv.w = (short)f2bf(o3);
      *(short4v*)(outb + (size_t)m * 4096 + base) = sv;
    } else {
      float4 ov; ov.x = o0; ov.y = o1; ov.z = o2; ov.w = o3;
      *(float4*)(outf + (size_t)m * 4096 + base) = ov;
    }
  }
}

// ------------------------------------------------------------------- RoPE ---
__global__ void rope_tab_kernel(float2* __restrict__ tab) {
  int idx = blockIdx.x * 256 + threadIdx.x;   // 768*64
  int s = idx >> 6, i = idx & 63;
  float inv = __expf(-(float)i * (9.210340371976184f / 64.f));  // 10000^(-i/64)
  float ang = (float)s * inv;
  float sn, cs;
  sincosf(ang, &sn, &cs);
  float2 r; r.x = cs; r.y = sn;
  tab[idx] = r;
}

__global__ __launch_bounds__(256) void rope_apply_kernel(float* __restrict__ qkv,
    const float2* __restrict__ tab) {
  int m = blockIdx.x;
  int s = m % 768;
  float* rowp = qkv + (size_t)m * 6144;
  for (int idx = threadIdx.x; idx < 2560; idx += 256) {   // 40 heads x 64 pairs
    int head = idx >> 6, i = idx & 63;
    int col = (head < 32) ? head * 128 : 4096 + (head - 32) * 128;
    float2 cs = tab[s * 64 + i];
    float x0 = rowp[col + i], x1 = rowp[col + i + 64];
    rowp[col + i]      = x0 * cs.x - x1 * cs.y;
    rowp[col + i + 64] = x1 * cs.x + x0 * cs.y;
  }
}

// ------------------------------------------------- MFMA flash attention -----
__global__ __launch_bounds__(256) void attn_mfma_kernel(const float* __restrict__ qkv,
    const int* __restrict__ amask, u16* __restrict__ attn_bf) {
  __shared__ u16 Ks[4][32][40];   // [kslice][key][8k-frag slots + pad]
  __shared__ u16 Vt[128][40];     // [d][key]
  __shared__ u16 Ps[4][16][40];   // per-wave [qrow][key]
  const int b = blockIdx.z, hh = blockIdx.y, q0 = blockIdx.x * 64;
  const int kvh = hh >> 2;
  const int tid = threadIdx.x, lane = tid & 63, w = tid >> 6;
  const int lrow = lane & 15, g = lane >> 4;
  const float sc = 0.08838834764831845f;   // 1/sqrt(128)

  short8 qf[4];
  {
    const float* qp = qkv + ((size_t)(b * 768 + q0 + w * 16 + lrow)) * 6144 + hh * 128;
#pragma unroll
    for (int ks = 0; ks < 4; ks++) {
      float4 lo = *(const float4*)(qp + ks * 32 + g * 8);
      float4 hi = *(const float4*)(qp + ks * 32 + g * 8 + 4);
      short8 sv;
      sv[0] = f2bf_hw(lo.x * sc); sv[1] = f2bf_hw(lo.y * sc);
      sv[2] = f2bf_hw(lo.z * sc); sv[3] = f2bf_hw(lo.w * sc);
      sv[4] = f2bf_hw(hi.x * sc); sv[5] = f2bf_hw(hi.y * sc);
      sv[6] = f2bf_hw(hi.z * sc); sv[7] = f2bf_hw(hi.w * sc);
      qf[ks] = sv;
    }
  }

  f32x4 acco[8] = {};
  float mrun[4] = {-1e30f, -1e30f, -1e30f, -1e30f};
  float lrun[4] = {0.f, 0.f, 0.f, 0.f};
  const int ntile = (q0 >> 5) + 2;

  for (int kt = 0; kt < ntile; kt++) {
    const int k0 = kt * 32;
    __syncthreads();
#pragma unroll
    for (int i = 0; i < 4; i++) {
      int idx = i * 256 + tid;
      int r2 = idx >> 5, c4 = (idx & 31) << 2;
      const float* kp = qkv + ((size_t)(b * 768 + k0 + r2)) * 6144 + 4096 + kvh * 128 + c4;
      float4 kv = *(const float4*)kp;
      short4v ksv;
      ksv.x = f2bf_hw(kv.x); ksv.y = f2bf_hw(kv.y);
      ksv.z = f2bf_hw(kv.z); ksv.w = f2bf_hw(kv.w);
      *(short4v*)&Ks[c4 >> 5][r2][c4 & 31] = ksv;
      float4 vv = *(const float4*)(kp + 1024);
      Vt[c4 + 0][r2] = (u16)f2bf_hw(vv.x);
      Vt[c4 + 1][r2] = (u16)f2bf_hw(vv.y);
      Vt[c4 + 2][r2] = (u16)f2bf_hw(vv.z);
      Vt[c4 + 3][r2] = (u16)f2bf_hw(vv.w);
    }
    __syncthreads();

    f32x4 s0 = {}, s1 = {};
#pragma unroll
    for (int ks = 0; ks < 4; ks++) {
      short8 kb0 = *(const short8*)&Ks[ks][lrow][g * 8];
      short8 kb1 = *(const short8*)&Ks[ks][16 + lrow][g * 8];
      s0 = __builtin_amdgcn_mfma_f32_16x16x32_bf16(qf[ks], kb0, s0, 0, 0, 0);
      s1 = __builtin_amdgcn_mfma_f32_16x16x32_bf16(qf[ks], kb1, s1, 0, 0, 0);
    }
    const int key0 = k0 + lrow, key1 = k0 + 16 + lrow;
    const bool am0 = amask[b * 768 + key0] != 0;
    const bool am1 = amask[b * 768 + key1] != 0;
    float scl4[4];
#pragma unroll
    for (int rr = 0; rr < 4; rr++) {
      int qrow = q0 + w * 16 + g * 4 + rr;
      float v0 = (key0 <= qrow && am0) ? s0[rr] : -1e30f;
      float v1 = (key1 <= qrow && am1) ? s1[rr] : -1e30f;
      float m = fmaxf(v0, v1);
      m = fmaxf(m, __shfl_xor(m, 1));
      m = fmaxf(m, __shfl_xor(m, 2));
      m = fmaxf(m, __shfl_xor(m, 4));
      m = fmaxf(m, __shfl_xor(m, 8));
      float mnew = fmaxf(mrun[rr], m);
      float scl = __expf(mrun[rr] - mnew);
      float p0 = __expf(v0 - mnew);
      float p1 = __expf(v1 - mnew);
      float ls = p0 + p1;
      ls += __shfl_xor(ls, 1);
      ls += __shfl_xor(ls, 2);
      ls += __shfl_xor(ls, 4);
      ls += __shfl_xor(ls, 8);
      lrun[rr] = lrun[rr] * scl + ls;
      mrun[rr] = mnew;
      scl4[rr] = scl;
      Ps[w][g * 4 + rr][lrow]      = (u16)f2bf_hw(p0);
      Ps[w][g * 4 + rr][16 + lrow] = (u16)f2bf_hw(p1);
    }
#pragma unroll
    for (int nf = 0; nf < 8; nf++)
#pragma unroll
      for (int rr = 0; rr < 4; rr++) acco[nf][rr] *= scl4[rr];

    asm volatile("s_waitcnt lgkmcnt(0)" ::: "memory");   // Ps writes landed
    __builtin_amdgcn_sched_barrier(0);
    short8 pa = *(const short8*)&Ps[w][lrow][g * 8];
#pragma unroll
    for (int nf = 0; nf < 8; nf++) {
      short8 vb = *(const short8*)&Vt[nf * 16 + lrow][g * 8];
      acco[nf] = __builtin_amdgcn_mfma_f32_16x16x32_bf16(pa, vb, acco[nf], 0, 0, 0);
    }
  }

#pragma unroll
  for (int rr = 0; rr < 4; rr++) {
    float inv = 1.f / lrun[rr];
    size_t orow = (size_t)(b * 768 + q0 + w * 16 + g * 4 + rr);
#pragma unroll
    for (int nf = 0; nf < 8; nf++)
      attn_bf[orow * 4096 + hh * 128 + nf * 16 + lrow] = f2bf(acco[nf][rr] * inv);
  }
}

// ------------------------------------------------------------ small utils ---
__global__ void convert_img_kernel(const float* __restrict__ in, u16* __restrict__ out) {
  int idx = blockIdx.x * 256 + threadIdx.x;   // chunks of 8; 640*1024/8 = 81920
  if (idx >= 81920) return;
  uint4 w = {0u, 0u, 0u, 0u};
  if (idx < 65792) {                          // real data: 514*1024/8
    const float* p = in + (size_t)idx * 8;
    float4 v0 = *(const float4*)p;
    float4 v1 = *(const float4*)(p + 4);
    w.x = (u32)f2bf(v0.x) | ((u32)f2bf(v0.y) << 16);
    w.y = (u32)f2bf(v0.z) | ((u32)f2bf(v0.w) << 16);
    w.z = (u32)f2bf(v1.x) | ((u32)f2bf(v1.y) << 16);
    w.w = (u32)f2bf(v1.z) | ((u32)f2bf(v1.w) << 16);
  }
  *(uint4*)(out + (size_t)idx * 8) = w;       // zero-fill pad rows 514..639
}

__global__ void embed_gather_kernel(const float* __restrict__ embed,
    const int* __restrict__ ids, float* __restrict__ h) {
  int row = blockIdx.x;                 // 0..1021
  int b = row / 511, tt = row % 511;
  int id = ids[b * 511 + tt];
  const float* src = embed + (size_t)id * 4096;
  float* dst = h + ((size_t)(b * 768 + 257 + tt)) * 4096;
  for (int i = threadIdx.x * 4; i < 4096; i += 1024)
    *(float4*)(dst + i) = *(const float4*)(src + i);
}

__global__ __launch_bounds__(256) void gu_combine_kernel(const u16* __restrict__ g,
    const u16* __restrict__ u, u16* __restrict__ x2) {
  size_t idx = (size_t)blockIdx.x * 256 + threadIdx.x;   // chunks of 8; 2752512 total
  uint4 gv = *(const uint4*)(g + idx * 8);
  uint4 uv = *(const uint4*)(u + idx * 8);
  u32 gi[4] = {gv.x, gv.y, gv.z, gv.w};
  u32 ui[4] = {uv.x, uv.y, uv.z, uv.w};
  u32 oi[4];
#pragma unroll
  for (int i = 0; i < 4; i++) {
    float g0 = bf2f((u16)(gi[i] & 0xffff)), g1 = bf2f((u16)(gi[i] >> 16));
    float u0 = bf2f((u16)(ui[i] & 0xffff)), u1 = bf2f((u16)(ui[i] >> 16));
    float s0 = g0 / (1.f + __expf(-g0)) * u0;
    float s1 = g1 / (1.f + __expf(-g1)) * u1;
    oi[i] = (u32)f2bf(s0) | ((u32)f2bf(s1) << 16);
  }
  uint4 ov; ov.x = oi[0]; ov.y = oi[1]; ov.z = oi[2]; ov.w = oi[3];
  *(uint4*)(x2 + idx * 8) = ov;
}

// ------------------------------------------------------------------ host ----
extern "C" void kernel_launch(void* const* d_in, const int* in_sizes, int n_in,
                              void* d_out, int out_size, void* d_ws, size_t ws_size,
                              hipStream_t stream) {
  const float* image_embeds = (const float*)d_in[0];
  const int*   input_ids    = (const int*)d_in[1];
  const int*   amask        = (const int*)d_in[2];
  const float* proj_W = (const float*)d_in[3];
  const float* proj_b = (const float*)d_in[4];
  const float* embed  = (const float*)d_in[5];
  const float* ln1 = (const float*)d_in[6];
  const float* ln2 = (const float*)d_in[7];
  const float* ln_f = (const float*)d_in[8];
  const float* Wq = (const float*)d_in[9];
  const float* Aq = (const float*)d_in[10];
  const float* Bq = (const float*)d_in[11];
  const float* Wk = (const float*)d_in[12];
  const float* Ak = (const float*)d_in[13];
  const float* Bk = (const float*)d_in[14];
  const float* Wv = (const float*)d_in[15];
  const float* Av = (const float*)d_in[16];
  const float* Bv = (const float*)d_in[17];
  const float* Wo = (const float*)d_in[18];
  const float* Ao = (const float*)d_in[19];
  const float* Bo = (const float*)d_in[20];
  const float* Wg = (const float*)d_in[21];
  const float* Ag = (const float*)d_in[22];
  const float* Bg = (const float*)d_in[23];
  const float* Wu = (const float*)d_in[24];
  const float* Au = (const float*)d_in[25];
  const float* Bu = (const float*)d_in[26];
  const float* Wd = (const float*)d_in[27];
  const float* Ad = (const float*)d_in[28];
  const float* Bd = (const float*)d_in[29];
  (void)in_sizes; (void)n_in; (void)out_size;

  char* ws = (char*)d_ws;
  size_t off = 0;
  auto alloc = [&](size_t bytes) -> void* {
    void* p = ws + off; off += (bytes + 255) & ~(size_t)255; return p;
  };
  float* h       = (float*) alloc((size_t)1536 * 4096 * 4);
  u16*   xn      = (u16*)   alloc((size_t)1536 * 4096 * 2);
  float* qkv     = (float*) alloc((size_t)1536 * 6144 * 4);
  u16*   attn_bf = (u16*)   alloc((size_t)1536 * 4096 * 2);
  u16*   g_bf    = (u16*)   alloc((size_t)1536 * 14336 * 2);
  u16*   u_bf    = (u16*)   alloc((size_t)1536 * 14336 * 2);
  u16*   x2_bf   = (u16*)   alloc((size_t)1536 * 14336 * 2);
  float* t       = (float*) alloc((size_t)1536 * 32 * 4);
  float2* tab    = (float2*)alloc((size_t)768 * 64 * 8);
  u16*   img_bf  = (u16*)   alloc((size_t)640 * 1024 * 2);       // 128-padded
  float* pc      = (float*) alloc((size_t)2 * 1536 * 4096 * 4);  // split-K partials
  // bf16 weight copies (all layers)
  const size_t nQ = (size_t)2 * 4096 * 4096;     // Wq / Wo
  const size_t nK = (size_t)2 * 1024 * 4096;     // Wk / Wv
  const size_t nG = (size_t)2 * 14336 * 4096;    // Wg / Wu / Wd
  const long nQl8 = 4096L * 4096 / 8, nKl8 = 1024L * 4096 / 8, nGl8 = 14336L * 4096 / 8;
  u16* wq_b = (u16*)alloc(nQ * 2);
  u16* wk_b = (u16*)alloc(nK * 2);
  u16* wv_b = (u16*)alloc(nK * 2);
  u16* wo_b = (u16*)alloc(nQ * 2);
  u16* wg_b = (u16*)alloc(nG * 2);
  u16* wu_b = (u16*)alloc(nG * 2);
  u16* wd_b = (u16*)alloc(nG * 2);
  const bool use_bf = (off <= ws_size);
  const int CONVY = 16;                          // sidecar y-blocks per launch

  dim3 blk(256);
  auto launch_gemm = [&](const GemmArgs& a, dim3 grid) {
    if (a.Wb0) gemm_kernel<1><<<grid, blk, 0, stream>>>(a);
    else       gemm_kernel<0><<<grid, blk, 0, stream>>>(a);
  };

  convert_img_kernel<<<dim3(320), blk, 0, stream>>>(image_embeds, img_bf);
  rope_tab_kernel<<<dim3(192), blk, 0, stream>>>(tab);

  { // projector -> h; sidecar: convert layer-0 Wq/Wk/Wv (consumed next launch)
    GemmArgs a = {};
    a.A = img_bf; a.M = 514; a.K = 1024; a.lda = 1024; a.ldw = 1024;
    a.W0 = proj_W;
    a.bias = proj_b;
    a.outf = h; a.ostride = 4096; a.rowremap = 1;
    a.ny_main = 32;
    dim3 grid(5, 32);
    if (use_bf) {
      a.cj[0] = {Wq, wq_b, nQl8};
      a.cj[1] = {Wk, wk_b, nKl8};
      a.cj[2] = {Wv, wv_b, nKl8};
      grid = dim3(5, 32 + 2 * CONVY);      // 160 sidecar blocks
    }
    launch_gemm(a, grid);
  }
  embed_gather_kernel<<<dim3(1022), blk, 0, stream>>>(embed, input_ids, h);

  for (int l = 0; l < 2; l++) {
    const float* Wq_l = Wq + (size_t)l * 4096 * 4096;
    const float* Aq_l = Aq + (size_t)l * 8 * 4096;
    const float* Bq_l = Bq + (size_t)l * 4096 * 8;
    const float* Wk_l = Wk + (size_t)l * 1024 * 4096;
    const float* Ak_l = Ak + (size_t)l * 8 * 4096;
    const float* Bk_l = Bk + (size_t)l * 1024 * 8;
    const float* Wv_l = Wv + (size_t)l * 1024 * 4096;
    const float* Av_l = Av + (size_t)l * 8 * 4096;
    const float* Bv_l = Bv + (size_t)l * 1024 * 8;
    const float* Wo_l = Wo + (size_t)l * 4096 * 4096;
    const float* Ao_l = Ao + (size_t)l * 8 * 4096;
    const float* Bo_l = Bo + (size_t)l * 4096 * 8;
    const float* Wg_l = Wg + (size_t)l * 14336 * 4096;
    const float* Ag_l = Ag + (size_t)l * 8 * 4096;
    const float* Bg_l = Bg + (size_t)l * 14336 * 8;
    const float* Wu_l = Wu + (size_t)l * 14336 * 4096;
    const float* Au_l = Au + (size_t)l * 8 * 4096;
    const float* Bu_l = Bu + (size_t)l * 14336 * 8;
    const float* Wd_l = Wd + (size_t)l * 4096 * 14336;
    const float* Ad_l = Ad + (size_t)l * 8 * 14336;
    const float* Bd_l = Bd + (size_t)l * 4096 * 8;
    u16* wq_bl = wq_b + (size_t)l * 4096 * 4096;
    u16* wk_bl = wk_b + (size_t)l * 1024 * 4096;
    u16* wv_bl = wv_b + (size_t)l * 1024 * 4096;
    u16* wo_bl = wo_b + (size_t)l * 4096 * 4096;
    u16* wg_bl = wg_b + (size_t)l * 14336 * 4096;
    u16* wu_bl = wu_b + (size_t)l * 14336 * 4096;
    u16* wd_bl = wd_b + (size_t)l * 14336 * 4096;

    rmsnorm_kernel<<<dim3(1536), blk, 0, stream>>>(h, ln1 + l * 4096, xn, (float*)nullptr);
    lora_xa_kernel<3><<<dim3(1536), blk, 0, stream>>>(xn, 4096, Aq_l, Ak_l, Av_l, t);
    { // fused QKV; sidecar: convert Wo_l, Wg_l
      GemmArgs a = {};
      a.A = xn; a.M = 1536; a.K = 4096; a.lda = 4096; a.ldw = 4096;
      a.W0 = Wq_l; a.LB0 = Bq_l; a.toff0 = 0;
      a.W1 = Wk_l; a.LB1 = Bk_l; a.toff1 = 8;
      a.W2 = Wv_l; a.LB2 = Bv_l; a.toff2 = 16;
      a.seg1 = 4096; a.seg2 = 5120;
      a.t = t; a.outf = qkv; a.ostride = 6144;
      a.ny_main = 48;
      dim3 grid(12, 48);
      if (use_bf) {
        a.Wb0 = wq_bl; a.Wb1 = wk_bl; a.Wb2 = wv_bl;
        a.cj[0] = {Wo_l, wo_bl, nQl8};
        a.cj[1] = {Wg_l, wg_bl, nGl8};
        grid = dim3(12, 48 + CONVY);
      }
      launch_gemm(a, grid);
    }
    rope_apply_kernel<<<dim3(1536), blk, 0, stream>>>(qkv, tab);
    attn_mfma_kernel<<<dim3(12, 32, 2), blk, 0, stream>>>(qkv, amask, attn_bf);
    lora_xa_kernel<1><<<dim3(1536), blk, 0, stream>>>(attn_bf, 4096, Ao_l,
        (const float*)nullptr, (const float*)nullptr, t);
    { // O projection (split-K x2); sidecar: convert Wu_l
      GemmArgs a = {};
      a.A = attn_bf; a.M = 1536; a.K = 2048; a.lda = 4096; a.ldw = 4096;
      a.W0 = Wo_l;
      a.ostride = 4096; a.outp = pc;
      a.ny_main = 32;
      dim3 grid(12, 32, 2);
      if (use_bf) {
        a.Wb0 = wo_bl;
        a.cj[0] = {Wu_l, wu_bl, nGl8};
        grid = dim3(12, 32 + CONVY, 2);
      }
      launch_gemm(a, grid);
      combine_kernel<<<dim3(1536), blk, 0, stream>>>(h, pc, t, Bo_l);
    }
    rmsnorm_kernel<<<dim3(1536), blk, 0, stream>>>(h, ln2 + l * 4096, xn, (float*)nullptr);
    lora_xa_kernel<2><<<dim3(1536), blk, 0, stream>>>(xn, 4096, Ag_l, Au_l,
        (const float*)nullptr, t);
    { // fused gate+up; sidecar: convert Wd_l
      GemmArgs a = {};
      a.A = xn; a.M = 1536; a.K = 4096; a.lda = 4096; a.ldw = 4096;
      a.W0 = Wg_l; a.LB0 = Bg_l; a.toff0 = 0;
      a.W1 = Wu_l; a.LB1 = Bu_l; a.toff1 = 8;
      a.seg1 = 14336;
      a.t = t; a.outb0 = g_bf; a.outb1 = u_bf; a.ostride = 14336;
      a.ny_main = 224;
      dim3 grid(12, 224);
      if (use_bf) {
        a.Wb0 = wg_bl; a.Wb1 = wu_bl;
        a.cj[0] = {Wd_l, wd_bl, nGl8};
        grid = dim3(12, 224 + CONVY);
      }
      launch_gemm(a, grid);
    }
    gu_combine_kernel<<<dim3(10752), blk, 0, stream>>>(g_bf, u_bf, x2_bf);
    lora_xa_kernel<1><<<dim3(1536), blk, 0, stream>>>(x2_bf, 14336, Ad_l,
        (const float*)nullptr, (const float*)nullptr, t);
    { // down projection (split-K x2); sidecar (l==0): convert layer-1 QKV w
      GemmArgs a = {};
      a.A = x2_bf; a.M = 1536; a.K = 7168; a.lda = 14336; a.ldw = 14336;
      a.W0 = Wd_l;
      a.ostride = 4096; a.outp = pc;
      a.ny_main = 32;
      dim3 grid(12, 32, 2);
      if (use_bf) {
        a.Wb0 = wd_bl;
        if (l == 0) {
          a.cj[0] = {Wq + (size_t)4096 * 4096, wq_b + (size_t)4096 * 4096, nQl8};
          a.cj[1] = {Wk + (size_t)1024 * 4096, wk_b + (size_t)1024 * 4096, nKl8};
          a.cj[2] = {Wv + (size_t)1024 * 4096, wv_b + (size_t)1024 * 4096, nKl8};
          grid = dim3(12, 32 + CONVY, 2);
        }
      }
      launch_gemm(a, grid);
      combine_kernel<<<dim3(1536), blk, 0, stream>>>(h, pc, t, Bd_l);
    }
  }
  rmsnorm_kernel<<<dim3(1536), blk, 0, stream>>>(h, ln_f, (u16*)nullptr, (float*)d_out);
}